// Round 10
// baseline (138.043 us; speedup 1.0000x reference)
//
#include <hip/hip_runtime.h>
#include <hip/hip_bf16.h>
#include <math.h>
#include <stdint.h>

// ---------------------------------------------------------------------------
// Attention (B=4, N=2048, D=512, H=8, Dh=64) for MI355X.
// Precision plan (threshold 6.48e-3 absolute; measured floor 1.95e-3):
//   x@Wqkv Q/K cols: 2-term (ah*bh + ah*bl); V cols 1-term.
//   QK^T: plain bf16.  PV: bf16 P,V.  AO bf16; out GEMM 1-term.
// R10: k_attn LDS-BW attack -> 64 q-rows/wave (4 q-groups share every K/V
// fragment read; K/V read traffic halved again). Grid 512, 2 waves/block,
// 48KB LDS (KV dbuf 32K + 2x8K P).
// ---------------------------------------------------------------------------

typedef unsigned short u16;
typedef __attribute__((ext_vector_type(4))) float f32x4;
typedef __attribute__((ext_vector_type(8))) short bf16x8;   // 8 bf16 = 4 VGPRs
typedef __attribute__((ext_vector_type(4))) short s16x4;

#define AS1 __attribute__((address_space(1)))
#define AS3 __attribute__((address_space(3)))
#define MFMA(a, b, c) __builtin_amdgcn_mfma_f32_16x16x32_bf16(a, b, c, 0, 0, 0)
#define QSCALE 0.180336880f   /* 0.125 * log2(e): logits in log2 domain */

__device__ __forceinline__ u16 f2bf(float f) {
  union { float f; unsigned u; } v; v.f = f;
  unsigned r = v.u + 0x7FFFu + ((v.u >> 16) & 1u);   // RNE
  return (u16)(r >> 16);
}
__device__ __forceinline__ float bf2f(u16 b) {
  union { unsigned u; float f; } v; v.u = ((unsigned)b) << 16; return v.f;
}
__device__ __forceinline__ void splitbf(float x, u16& hi, u16& lo) {
  hi = f2bf(x); lo = f2bf(x - bf2f(hi));
}
__device__ __forceinline__ void gld16(const u16* g, u16* l) {
  __builtin_amdgcn_global_load_lds((const AS1 void*)g, (AS3 void*)l, 16, 0, 0);
}
__device__ __forceinline__ float u2f(unsigned u) {
  union { unsigned u; float f; } v; v.u = u; return v.f;
}
__device__ __forceinline__ unsigned f2u(float f) {
  union { float f; unsigned u; } v; v.f = f; return v.u;
}
__device__ __forceinline__ int cvtpk(float lo, float hi) {
  int r; asm("v_cvt_pk_bf16_f32 %0, %1, %2" : "=v"(r) : "v"(lo), "v"(hi));
  return r;
}
__device__ __forceinline__ float fexp2(float x) {
  float r; asm("v_exp_f32 %0, %1" : "=v"(r) : "v"(x));
  return r;
}

// ---------------- prep kernels -------------------------------------------
__global__ void k_cast(const float* __restrict__ s, u16* __restrict__ h, int n) {
  int i = (blockIdx.x * 256 + threadIdx.x) * 4;
  if (i < n) {
    f32x4 v = *(const f32x4*)&s[i];
    s16x4 hh;
    #pragma unroll
    for (int j = 0; j < 4; ++j) hh[j] = (short)f2bf(v[j]);
    *(s16x4*)&h[i] = hh;
  }
}

// src [512][N] row-major -> dst [N][512] (transposed), split hi/lo
__global__ void k_tsplit(const float* __restrict__ s, u16* __restrict__ h,
                         u16* __restrict__ l, int N, int total) {
  int i = blockIdx.x * 256 + threadIdx.x;          // i = n*512 + k
  if (i < total) {
    int n = i >> 9, k = i & 511;
    u16 a, b; splitbf(s[(size_t)k * N + n], a, b);
    h[i] = a; l[i] = b;
  }
}

// ---------------- shared GEMM core: C[128x128] tile, K=512, BK=32 ----------
// TERMS=1: ah*bh.  TERMS=2: ah*bh + ah*bl (exact-x_hat * W).
template <int TERMS>
__device__ __forceinline__ void gemm_core(
    const u16* __restrict__ Ah,
    const u16* __restrict__ Bh, const u16* __restrict__ Bl,
    char* sm, int rowA, int rowB, int tid, f32x4 (&acc)[4][4]) {
  const int wid = tid >> 6, lane = tid & 63;
  const int x = lane & 15, h = lane >> 4;
  const int wr = wid >> 1, wc = wid & 1;
  const int d0 = wid * 1024 + lane * 16;
  const int lg0 = d0 ^ (((d0 >> 7) & 7) << 4);
  const int srow = lg0 >> 6;
  const int scol = (lg0 & 63) >> 1;
  const int swk = ((lane >> 1) & 7) << 4;
  const char* smA = sm + (((wr * 64 + x) * 64 + h * 16) ^ swk);
  const char* smB = sm + (((wc * 64 + x) * 64 + h * 16) ^ swk);

  for (int kt = 0; kt < 16; ++kt) {
    const int kofs = kt * 32;
    __syncthreads();
    #pragma unroll
    for (int r = 0; r < 2; ++r) {
      const int row  = r * 64 + srow;
      const int ldst = r * 4096 + wid * 1024;
      const size_t ga = (size_t)(rowA + row) * 512 + kofs + scol;
      const size_t gb = (size_t)(rowB + row) * 512 + kofs + scol;
      gld16(Ah + ga, (u16*)(sm + ldst));
      gld16(Bh + gb, (u16*)(sm + 16384 + ldst));
      if (TERMS == 2) gld16(Bl + gb, (u16*)(sm + 24576 + ldst));
    }
    __syncthreads();
    bf16x8 a_h[4], b_h[4], b_l[4];
    #pragma unroll
    for (int i = 0; i < 4; ++i)
      a_h[i] = *(const bf16x8*)(smA + i * 1024);
    #pragma unroll
    for (int j = 0; j < 4; ++j) {
      b_h[j] = *(const bf16x8*)(smB + 16384 + j * 1024);
      if (TERMS == 2) b_l[j] = *(const bf16x8*)(smB + 24576 + j * 1024);
    }
    __builtin_amdgcn_s_setprio(1);
    #pragma unroll
    for (int i = 0; i < 4; ++i)
      #pragma unroll
      for (int j = 0; j < 4; ++j) {
        acc[i][j] = MFMA(a_h[i], b_h[j], acc[i][j]);
        if (TERMS == 2) acc[i][j] = MFMA(a_h[i], b_l[j], acc[i][j]);
      }
    __builtin_amdgcn_s_setprio(0);
  }
}

// ---------------- QKV projection -------------------------------------------
__global__ __launch_bounds__(256) void k_gemm_qkv(
    const u16* __restrict__ Ah,
    const u16* __restrict__ Bh, const u16* __restrict__ Bl,
    u16* __restrict__ Qb, u16* __restrict__ Kb, u16* __restrict__ Vt) {
  __shared__ __align__(1024) char sm[32768];
  const int tid = threadIdx.x, lane = tid & 63, wid = tid >> 6;
  const int x = lane & 15, h = lane >> 4;
  const int wr = wid >> 1, wc = wid & 1;
  const int rowA = blockIdx.x * 128, rowB = blockIdx.y * 128;
  f32x4 acc[4][4] = {};
  if (rowB >= 1024)
    gemm_core<1>(Ah, Bh, Bl, sm, rowA, rowB, tid, acc);
  else
    gemm_core<2>(Ah, Bh, Bl, sm, rowA, rowB, tid, acc);

  #pragma unroll
  for (int i = 0; i < 4; ++i)
    #pragma unroll
    for (int j = 0; j < 4; ++j) {
      const int n = rowB + wc * 64 + j * 16 + x;
      const int which = n >> 9;
      const int hh = (n >> 6) & 7, d = n & 63;
      const int m0 = rowA + wr * 64 + i * 16 + h * 4;
      const int b = m0 >> 11, is0 = m0 & 2047;
      if (which == 0) {
        #pragma unroll
        for (int r = 0; r < 4; ++r) {
          const size_t idx = ((size_t)((b * 8 + hh) * 2048 + is0 + r)) * 64 + d;
          Qb[idx] = f2bf(acc[i][j][r] * QSCALE);
        }
      } else if (which == 1) {
        #pragma unroll
        for (int r = 0; r < 4; ++r) {
          const size_t idx = ((size_t)((b * 8 + hh) * 2048 + is0 + r)) * 64 + d;
          Kb[idx] = f2bf(acc[i][j][r]);
        }
      } else {
        s16x4 vv;
        #pragma unroll
        for (int r = 0; r < 4; ++r) vv[r] = (short)f2bf(acc[i][j][r]);
        *(s16x4*)&Vt[((size_t)((b * 8 + hh) * 64 + d)) * 2048 + is0] = vv;
      }
    }
}

// ---------------- output projection (1-term bf16) --------------------------
__global__ __launch_bounds__(256) void k_gemm_out(
    const u16* __restrict__ Ah, const u16* __restrict__ Bh,
    const float* __restrict__ bias, float* __restrict__ out) {
  __shared__ __align__(1024) char sm[32768];
  const int tid = threadIdx.x, lane = tid & 63, wid = tid >> 6;
  const int x = lane & 15, h = lane >> 4;
  const int wr = wid >> 1, wc = wid & 1;
  const int rowA = blockIdx.x * 128, rowB = blockIdx.y * 128;
  f32x4 acc[4][4] = {};
  gemm_core<1>(Ah, Bh, Bh, sm, rowA, rowB, tid, acc);

  #pragma unroll
  for (int i = 0; i < 4; ++i)
    #pragma unroll
    for (int j = 0; j < 4; ++j) {
      const int n = rowB + wc * 64 + j * 16 + x;
      #pragma unroll
      for (int r = 0; r < 4; ++r) {
        const int m = rowA + wr * 64 + i * 16 + h * 4 + r;
        out[(size_t)m * 512 + n] = acc[i][j][r] + bias[n];
      }
    }
}

// ---------------- flash attention (16x16 MFMA, 64 q/wave) -------------------
// Grid 512 blocks (XCD-swizzled), 128 thr = 2 waves x 64 q-rows (QBLK=128).
// KV tile 64.  Per wave: 4 q-groups of 16 share every K/V fragment read.
// Swapped QK^T per group (bf16): lane (x,h) holds S^T[k=c*16+h*4+r][q=g*16+x].
// P -> per-wave LDS [64 q][64 kv] (128B rows, ^((q&7)<<4) swizzle), read
// back as PV A-frags.  Row-sum via MFMA(P, ones).  Defer-rescale THR=7.
// LDS: KV dbuf 2x16KB + per-wave P 8KB = 48KB.
__global__ __launch_bounds__(128, 2) void k_attn(
    const u16* __restrict__ Qb,
    const u16* __restrict__ Kb, const u16* __restrict__ Vt,
    u16* __restrict__ AO) {
  __shared__ __align__(1024) char sm[49152];
  const int tid = threadIdx.x, wid = tid >> 6, lane = tid & 63;
  const int x = lane & 15, h = lane >> 4;

  // XCD-aware swizzle (512 % 8 == 0): 4 consecutive bh per XCD (2MB KV in L2)
  const int fid = blockIdx.x;
  const int l = (fid & 7) * 64 + (fid >> 3);
  const int qb = l & 15, bh = l >> 4;

  const size_t base = (size_t)bh * 2048 * 64;   // Q/K [bh][2048][64]; Vt [bh][64][2048]
  const int qr0 = qb * 128 + wid * 64;

  // Q B-frags per group g: lane (x,h) holds Q[qr0+g*16+x][d=ks*32+h*8+j]
  bf16x8 qh[4][2];
  #pragma unroll
  for (int g = 0; g < 4; ++g) {
    const size_t rq = base + (size_t)(qr0 + g * 16 + x) * 64 + h * 8;
    #pragma unroll
    for (int ks = 0; ks < 2; ++ks)
      qh[g][ks] = *(const bf16x8*)&Qb[rq + ks * 32];
  }

  bf16x8 ones;
  #pragma unroll
  for (int j = 0; j < 8; ++j) ones[j] = (short)0x3F80;   // bf16 1.0

  // staging map (128 thr): dest byte db = r*2048 + tid*16 per 4KB chunk
  int srow[2], scb[2];
  #pragma unroll
  for (int r = 0; r < 2; ++r) {
    const int db = r * 2048 + tid * 16;
    const int lg = db ^ (((db >> 7) & 7) << 4);
    srow[r] = lg >> 6;
    scb[r] = (lg & 63) >> 1;
  }

  const int swk = ((lane >> 1) & 7) << 4;   // read xor for 64B-row tiles
  const int rdo = (x * 64 + h * 16) ^ swk;  // per-lane K/V read base offset
  char* const pb = sm + 32768 + wid * 8192; // per-wave P buffer [64q][64kv]
  const int pxor = (x & 7) << 4;            // P row swizzle

  float mrun[4] = {-INFINITY, -INFINITY, -INFINITY, -INFINITY};
  f32x4 o[4][4] = {};
  f32x4 os[4] = {};

  {  // stage tile 0 -> buf0
    #pragma unroll
    for (int r = 0; r < 2; ++r) {
      const size_t kR = base + (size_t)srow[r] * 64 + scb[r];
      const size_t vR = base + (size_t)srow[r] * 2048 + scb[r];
      const int db = r * 2048 + tid * 16;
      gld16(Kb + kR,      (u16*)(sm + db));
      gld16(Kb + kR + 32, (u16*)(sm + 4096 + db));
      gld16(Vt + vR,      (u16*)(sm + 8192 + db));
      gld16(Vt + vR + 32, (u16*)(sm + 12288 + db));
    }
  }

  for (int kv = 0; kv < 32; ++kv) {
    const int bb = (kv & 1) * 16384;
    __builtin_amdgcn_s_barrier();
    if (kv < 31) {
      const size_t kvb = (size_t)(kv + 1) * 64;
      char* buf = sm + (16384 - bb);
      #pragma unroll
      for (int r = 0; r < 2; ++r) {
        const size_t kR = base + (kvb + srow[r]) * 64 + scb[r];
        const size_t vR = base + (size_t)srow[r] * 2048 + kvb + scb[r];
        const int db = r * 2048 + tid * 16;
        gld16(Kb + kR,      (u16*)(buf + db));
        gld16(Kb + kR + 32, (u16*)(buf + 4096 + db));
        gld16(Vt + vR,      (u16*)(buf + 8192 + db));
        gld16(Vt + vR + 32, (u16*)(buf + 12288 + db));
      }
      asm volatile("s_waitcnt vmcnt(8)" ::: "memory");
    } else {
      asm volatile("s_waitcnt vmcnt(0)" ::: "memory");
    }
    __builtin_amdgcn_s_barrier();

    const char* smb = sm + bb + rdo;

    // ---- S^T = K Q^T (bf16; Q pre-scaled by 0.125*log2e); 4 groups share K
    f32x4 s[4][4] = {};
    __builtin_amdgcn_s_setprio(1);
    #pragma unroll
    for (int c = 0; c < 4; ++c)
      #pragma unroll
      for (int ks = 0; ks < 2; ++ks) {
        bf16x8 kb_ = *(const bf16x8*)(smb + ks * 4096 + c * 1024);
        #pragma unroll
        for (int g = 0; g < 4; ++g)
          s[g][c] = MFMA(kb_, qh[g][ks], s[g][c]);
      }
    __builtin_amdgcn_s_setprio(0);

    // ---- per-group row max (16 local) + 2-shfl cross reduce over h-lanes
    float pm[4];
    #pragma unroll
    for (int g = 0; g < 4; ++g) {
      float m0 = fmaxf(fmaxf(s[g][0][0], s[g][0][1]), s[g][0][2]);
      float m1 = fmaxf(fmaxf(s[g][0][3], s[g][1][0]), s[g][1][1]);
      float m2 = fmaxf(fmaxf(s[g][1][2], s[g][1][3]), s[g][2][0]);
      float m3 = fmaxf(fmaxf(s[g][2][1], s[g][2][2]), s[g][2][3]);
      float m4 = fmaxf(fmaxf(s[g][3][0], s[g][3][1]), s[g][3][2]);
      float m5 = fmaxf(fmaxf(m0, m1), m2);
      float p  = fmaxf(fmaxf(fmaxf(m3, m4), s[g][3][3]), m5);
      p = fmaxf(p, __shfl_xor(p, 16, 64));
      p = fmaxf(p, __shfl_xor(p, 32, 64));
      pm[g] = p;
    }

    // ---- defer-rescale (THR=7 in log2; P bounded by 128)
    if (__any((pm[0] > mrun[0] + 7.0f) || (pm[1] > mrun[1] + 7.0f) ||
              (pm[2] > mrun[2] + 7.0f) || (pm[3] > mrun[3] + 7.0f))) {
      #pragma unroll
      for (int g = 0; g < 4; ++g) {
        float mnew = fmaxf(mrun[g], pm[g]);
        float scl = fexp2(mrun[g] - mnew);
        mrun[g] = mnew;
        #pragma unroll
        for (int r = 0; r < 4; ++r) {
          float sq = u2f((unsigned)__builtin_amdgcn_ds_bpermute(
              (20 * h + r) * 4, (int)f2u(scl)));
          os[g][r] *= sq;
          #pragma unroll
          for (int dg = 0; dg < 4; ++dg) o[g][dg][r] *= sq;
        }
      }
    }

    // ---- P = exp2(S - mrun) -> bf16 pairs -> per-wave LDS [64q][64kv]
    #pragma unroll
    for (int g = 0; g < 4; ++g)
      #pragma unroll
      for (int c = 0; c < 4; ++c) {
        int w0 = cvtpk(fexp2(s[g][c][0] - mrun[g]),
                       fexp2(s[g][c][1] - mrun[g]));
        int w1 = cvtpk(fexp2(s[g][c][2] - mrun[g]),
                       fexp2(s[g][c][3] - mrun[g]));
        int* dst = (int*)(pb + (g * 16 + x) * 128 + ((c * 32 + h * 8) ^ pxor));
        dst[0] = w0; dst[1] = w1;
      }

    // ---- PV + row-sum (P A-frags re-read from LDS; same-wave, no barrier)
    __builtin_amdgcn_s_setprio(1);
    #pragma unroll
    for (int ch = 0; ch < 2; ++ch) {
      bf16x8 pa[4];
      #pragma unroll
      for (int g = 0; g < 4; ++g)
        pa[g] = *(const bf16x8*)(pb + (g * 16 + x) * 128 +
                                 ((ch * 64 + h * 16) ^ pxor));
      #pragma unroll
      for (int g = 0; g < 4; ++g)
        os[g] = MFMA(pa[g], ones, os[g]);
      #pragma unroll
      for (int dg = 0; dg < 4; ++dg) {
        bf16x8 vb = *(const bf16x8*)(smb + 8192 + ch * 4096 + dg * 1024);
        #pragma unroll
        for (int g = 0; g < 4; ++g)
          o[g][dg] = MFMA(pa[g], vb, o[g][dg]);
      }
    }
    __builtin_amdgcn_s_setprio(0);
  }

  // ---- normalize (os[g][r] = rowsum for q = g*16+h*4+r), write AO bf16
  const int b_ = bh >> 3, head = bh & 7;
  #pragma unroll
  for (int g = 0; g < 4; ++g)
    #pragma unroll
    for (int r = 0; r < 4; ++r) {
      const float inv = 1.0f / os[g][r];
      const int row = qr0 + g * 16 + h * 4 + r;
      #pragma unroll
      for (int dg = 0; dg < 4; ++dg) {
        AO[((size_t)(b_ * 2048 + row)) * 512 + head * 64 + dg * 16 + x] =
            f2bf(o[g][dg][r] * inv);
      }
    }
}

// ---------------------------------------------------------------------------
extern "C" void kernel_launch(void* const* d_in, const int* in_sizes, int n_in,
                              void* d_out, int out_size, void* d_ws, size_t ws_size,
                              hipStream_t stream) {
  const float* x    = (const float*)d_in[0];
  const float* wqkv = (const float*)d_in[1];
  const float* wout = (const float*)d_in[2];
  const float* bout = (const float*)d_in[3];
  float* out = (float*)d_out;

  char* w = (char*)d_ws;
  u16* xh  = (u16*)(w + 0);           // 8192x512 bf16
  u16* wqh = (u16*)(w + 16777216);    // WqkvT [1536][512]
  u16* wql = (u16*)(w + 18350080);
  u16* woh = (u16*)(w + 19922944);    // WoutT [512][512]
  u16* wol = (u16*)(w + 20447232);    // (written, unused)
  u16* Qb  = (u16*)(w + 20971520);    // [32][2048][64] bf16 (pre-scaled)
  u16* Kb  = (u16*)(w + 37748736);    // [32][2048][64] bf16
  u16* Vt  = (u16*)(w + 46137344);    // [32][64][2048] bf16
  u16* AO  = (u16*)(w + 54525952);    // [8192][512] bf16; end 62914560

  k_cast  <<<4096, 256, 0, stream>>>(x, xh, 4194304);
  k_tsplit<<<3072, 256, 0, stream>>>(wqkv, wqh, wql, 1536, 786432);
  k_tsplit<<<1024, 256, 0, stream>>>(wout, woh, wol, 512, 262144);
  k_gemm_qkv<<<dim3(64, 12), 256, 0, stream>>>(xh, wqh, wql, Qb, Kb, Vt);
  k_attn<<<512, 128, 0, stream>>>(Qb, Kb, Vt, AO);
  k_gemm_out<<<dim3(64, 4), 256, 0, stream>>>(AO, woh, bout, out);
}

// Round 11
// 107.111 us; speedup vs baseline: 1.2888x; 1.2888x over previous
//
#include <hip/hip_runtime.h>
#include <hip/hip_bf16.h>
#include <math.h>
#include <stdint.h>

// ---------------------------------------------------------------------------
// Attention (B=4, N=2048, D=512, H=8, Dh=64) for MI355X.
// Precision plan (threshold 6.48e-3 absolute; measured floor 1.95e-3):
//   x@Wqkv Q/K cols: 2-term (ah*bh + ah*bl); V cols 1-term.
//   QK^T: plain bf16.  PV: bf16 P,V.  AO bf16; out GEMM 1-term.
// R11: R9 per-wave structure (32 q/wave, KV tile 64) but 4-wave/256-thr
// blocks, QBLK=128, grid 512 -> KV staged once per 128 q rows, LDS 48KB,
// 3 blocks/CU = 12 waves/CU (occupancy 18%->~37% cap). R10's 64-q/wave
// variant regressed (latency-bound at 4 waves/CU) -> reverted.
// ---------------------------------------------------------------------------

typedef unsigned short u16;
typedef __attribute__((ext_vector_type(4))) float f32x4;
typedef __attribute__((ext_vector_type(8))) short bf16x8;   // 8 bf16 = 4 VGPRs
typedef __attribute__((ext_vector_type(4))) short s16x4;

#define AS1 __attribute__((address_space(1)))
#define AS3 __attribute__((address_space(3)))
#define MFMA(a, b, c) __builtin_amdgcn_mfma_f32_16x16x32_bf16(a, b, c, 0, 0, 0)
#define QSCALE 0.180336880f   /* 0.125 * log2(e): logits in log2 domain */

__device__ __forceinline__ u16 f2bf(float f) {
  union { float f; unsigned u; } v; v.f = f;
  unsigned r = v.u + 0x7FFFu + ((v.u >> 16) & 1u);   // RNE
  return (u16)(r >> 16);
}
__device__ __forceinline__ float bf2f(u16 b) {
  union { unsigned u; float f; } v; v.u = ((unsigned)b) << 16; return v.f;
}
__device__ __forceinline__ void splitbf(float x, u16& hi, u16& lo) {
  hi = f2bf(x); lo = f2bf(x - bf2f(hi));
}
__device__ __forceinline__ void gld16(const u16* g, u16* l) {
  __builtin_amdgcn_global_load_lds((const AS1 void*)g, (AS3 void*)l, 16, 0, 0);
}
__device__ __forceinline__ float u2f(unsigned u) {
  union { unsigned u; float f; } v; v.u = u; return v.f;
}
__device__ __forceinline__ unsigned f2u(float f) {
  union { float f; unsigned u; } v; v.f = f; return v.u;
}
__device__ __forceinline__ int cvtpk(float lo, float hi) {
  int r; asm("v_cvt_pk_bf16_f32 %0, %1, %2" : "=v"(r) : "v"(lo), "v"(hi));
  return r;
}
__device__ __forceinline__ float fexp2(float x) {
  float r; asm("v_exp_f32 %0, %1" : "=v"(r) : "v"(x));
  return r;
}

// ---------------- prep kernels -------------------------------------------
__global__ void k_cast(const float* __restrict__ s, u16* __restrict__ h, int n) {
  int i = (blockIdx.x * 256 + threadIdx.x) * 4;
  if (i < n) {
    f32x4 v = *(const f32x4*)&s[i];
    s16x4 hh;
    #pragma unroll
    for (int j = 0; j < 4; ++j) hh[j] = (short)f2bf(v[j]);
    *(s16x4*)&h[i] = hh;
  }
}

// src [512][N] row-major -> dst [N][512] (transposed), split hi/lo
__global__ void k_tsplit(const float* __restrict__ s, u16* __restrict__ h,
                         u16* __restrict__ l, int N, int total) {
  int i = blockIdx.x * 256 + threadIdx.x;          // i = n*512 + k
  if (i < total) {
    int n = i >> 9, k = i & 511;
    u16 a, b; splitbf(s[(size_t)k * N + n], a, b);
    h[i] = a; l[i] = b;
  }
}

// ---------------- shared GEMM core: C[128x128] tile, K=512, BK=32 ----------
// TERMS=1: ah*bh.  TERMS=2: ah*bh + ah*bl (exact-x_hat * W).
template <int TERMS>
__device__ __forceinline__ void gemm_core(
    const u16* __restrict__ Ah,
    const u16* __restrict__ Bh, const u16* __restrict__ Bl,
    char* sm, int rowA, int rowB, int tid, f32x4 (&acc)[4][4]) {
  const int wid = tid >> 6, lane = tid & 63;
  const int x = lane & 15, h = lane >> 4;
  const int wr = wid >> 1, wc = wid & 1;
  const int d0 = wid * 1024 + lane * 16;
  const int lg0 = d0 ^ (((d0 >> 7) & 7) << 4);
  const int srow = lg0 >> 6;
  const int scol = (lg0 & 63) >> 1;
  const int swk = ((lane >> 1) & 7) << 4;
  const char* smA = sm + (((wr * 64 + x) * 64 + h * 16) ^ swk);
  const char* smB = sm + (((wc * 64 + x) * 64 + h * 16) ^ swk);

  for (int kt = 0; kt < 16; ++kt) {
    const int kofs = kt * 32;
    __syncthreads();
    #pragma unroll
    for (int r = 0; r < 2; ++r) {
      const int row  = r * 64 + srow;
      const int ldst = r * 4096 + wid * 1024;
      const size_t ga = (size_t)(rowA + row) * 512 + kofs + scol;
      const size_t gb = (size_t)(rowB + row) * 512 + kofs + scol;
      gld16(Ah + ga, (u16*)(sm + ldst));
      gld16(Bh + gb, (u16*)(sm + 16384 + ldst));
      if (TERMS == 2) gld16(Bl + gb, (u16*)(sm + 24576 + ldst));
    }
    __syncthreads();
    bf16x8 a_h[4], b_h[4], b_l[4];
    #pragma unroll
    for (int i = 0; i < 4; ++i)
      a_h[i] = *(const bf16x8*)(smA + i * 1024);
    #pragma unroll
    for (int j = 0; j < 4; ++j) {
      b_h[j] = *(const bf16x8*)(smB + 16384 + j * 1024);
      if (TERMS == 2) b_l[j] = *(const bf16x8*)(smB + 24576 + j * 1024);
    }
    __builtin_amdgcn_s_setprio(1);
    #pragma unroll
    for (int i = 0; i < 4; ++i)
      #pragma unroll
      for (int j = 0; j < 4; ++j) {
        acc[i][j] = MFMA(a_h[i], b_h[j], acc[i][j]);
        if (TERMS == 2) acc[i][j] = MFMA(a_h[i], b_l[j], acc[i][j]);
      }
    __builtin_amdgcn_s_setprio(0);
  }
}

// ---------------- QKV projection -------------------------------------------
__global__ __launch_bounds__(256) void k_gemm_qkv(
    const u16* __restrict__ Ah,
    const u16* __restrict__ Bh, const u16* __restrict__ Bl,
    u16* __restrict__ Qb, u16* __restrict__ Kb, u16* __restrict__ Vt) {
  __shared__ __align__(1024) char sm[32768];
  const int tid = threadIdx.x, lane = tid & 63, wid = tid >> 6;
  const int x = lane & 15, h = lane >> 4;
  const int wr = wid >> 1, wc = wid & 1;
  const int rowA = blockIdx.x * 128, rowB = blockIdx.y * 128;
  f32x4 acc[4][4] = {};
  if (rowB >= 1024)
    gemm_core<1>(Ah, Bh, Bl, sm, rowA, rowB, tid, acc);
  else
    gemm_core<2>(Ah, Bh, Bl, sm, rowA, rowB, tid, acc);

  #pragma unroll
  for (int i = 0; i < 4; ++i)
    #pragma unroll
    for (int j = 0; j < 4; ++j) {
      const int n = rowB + wc * 64 + j * 16 + x;
      const int which = n >> 9;
      const int hh = (n >> 6) & 7, d = n & 63;
      const int m0 = rowA + wr * 64 + i * 16 + h * 4;
      const int b = m0 >> 11, is0 = m0 & 2047;
      if (which == 0) {
        #pragma unroll
        for (int r = 0; r < 4; ++r) {
          const size_t idx = ((size_t)((b * 8 + hh) * 2048 + is0 + r)) * 64 + d;
          Qb[idx] = f2bf(acc[i][j][r] * QSCALE);
        }
      } else if (which == 1) {
        #pragma unroll
        for (int r = 0; r < 4; ++r) {
          const size_t idx = ((size_t)((b * 8 + hh) * 2048 + is0 + r)) * 64 + d;
          Kb[idx] = f2bf(acc[i][j][r]);
        }
      } else {
        s16x4 vv;
        #pragma unroll
        for (int r = 0; r < 4; ++r) vv[r] = (short)f2bf(acc[i][j][r]);
        *(s16x4*)&Vt[((size_t)((b * 8 + hh) * 64 + d)) * 2048 + is0] = vv;
      }
    }
}

// ---------------- output projection (1-term bf16) --------------------------
__global__ __launch_bounds__(256) void k_gemm_out(
    const u16* __restrict__ Ah, const u16* __restrict__ Bh,
    const float* __restrict__ bias, float* __restrict__ out) {
  __shared__ __align__(1024) char sm[32768];
  const int tid = threadIdx.x, lane = tid & 63, wid = tid >> 6;
  const int x = lane & 15, h = lane >> 4;
  const int wr = wid >> 1, wc = wid & 1;
  const int rowA = blockIdx.x * 128, rowB = blockIdx.y * 128;
  f32x4 acc[4][4] = {};
  gemm_core<1>(Ah, Bh, Bh, sm, rowA, rowB, tid, acc);

  #pragma unroll
  for (int i = 0; i < 4; ++i)
    #pragma unroll
    for (int j = 0; j < 4; ++j) {
      const int n = rowB + wc * 64 + j * 16 + x;
      #pragma unroll
      for (int r = 0; r < 4; ++r) {
        const int m = rowA + wr * 64 + i * 16 + h * 4 + r;
        out[(size_t)m * 512 + n] = acc[i][j][r] + bias[n];
      }
    }
}

// ---------------- flash attention (16x16 MFMA, 32 q/wave, 4 waves) ----------
// Grid 512 blocks (XCD-swizzled), 256 thr = 4 waves x 32 q-rows (QBLK=128).
// KV tile 64 staged ONCE per 128 q rows (4 waves share).  Per wave: 2
// q-groups of 16 share every K/V fragment read.  Swapped QK^T (bf16):
// lane (x,h) holds S^T[k=c*16+h*4+r][q=g*16+x].  P -> per-wave LDS
// [32 q][64 kv] (128B rows, ^((q&7)<<4) swizzle) -> PV A-frags.  Row-sum
// via MFMA(P, ones).  Defer-rescale THR=7.
// LDS: KV dbuf 2x16KB + 4x per-wave P 4KB = 48KB -> 3 blocks/CU.
__global__ __launch_bounds__(256, 3) void k_attn(
    const u16* __restrict__ Qb,
    const u16* __restrict__ Kb, const u16* __restrict__ Vt,
    u16* __restrict__ AO) {
  __shared__ __align__(1024) char sm[49152];
  const int tid = threadIdx.x, wid = tid >> 6, lane = tid & 63;
  const int x = lane & 15, h = lane >> 4;

  // XCD-aware swizzle (512 % 8 == 0): 4 consecutive bh per XCD (2MB KV in L2)
  const int fid = blockIdx.x;
  const int l = (fid & 7) * 64 + (fid >> 3);
  const int qb = l & 15, bh = l >> 4;

  const size_t base = (size_t)bh * 2048 * 64;   // Q/K [bh][2048][64]; Vt [bh][64][2048]
  const int qr0 = qb * 128 + wid * 32;

  // Q B-frags per group g: lane (x,h) holds Q[qr0+g*16+x][d=ks*32+h*8+j]
  bf16x8 qh[2][2];
  #pragma unroll
  for (int g = 0; g < 2; ++g) {
    const size_t rq = base + (size_t)(qr0 + g * 16 + x) * 64 + h * 8;
    #pragma unroll
    for (int ks = 0; ks < 2; ++ks)
      qh[g][ks] = *(const bf16x8*)&Qb[rq + ks * 32];
  }

  bf16x8 ones;
  #pragma unroll
  for (int j = 0; j < 8; ++j) ones[j] = (short)0x3F80;   // bf16 1.0

  // staging map (256 thr): dest byte db = tid*16 within each 4KB chunk
  const int db = tid * 16;
  const int lg = db ^ (((db >> 7) & 7) << 4);
  const int srow = lg >> 6;             // 0..63
  const int scb  = (lg & 63) >> 1;      // u16 col within 32-wide row
  const size_t offK = (size_t)srow * 64 + scb;
  const size_t offV = (size_t)srow * 2048 + scb;

  const int swk = ((lane >> 1) & 7) << 4;   // read xor for 64B-row tiles
  const int rdo = (x * 64 + h * 16) ^ swk;  // per-lane K/V read base offset
  char* const pb = sm + 32768 + wid * 4096; // per-wave P buffer [32q][64kv]
  const int pxor = (x & 7) << 4;            // P row swizzle
  const int prow = x * 128;                 // P row base (g adds 2048)

  float mrun[2] = {-INFINITY, -INFINITY};
  f32x4 o[2][4] = {};
  f32x4 os[2] = {};

  {  // stage tile 0 -> buf0 (4 loads/thread)
    gld16(Kb + base + offK,      (u16*)(sm + db));
    gld16(Kb + base + offK + 32, (u16*)(sm + 4096 + db));
    gld16(Vt + base + offV,      (u16*)(sm + 8192 + db));
    gld16(Vt + base + offV + 32, (u16*)(sm + 12288 + db));
  }

  for (int kv = 0; kv < 32; ++kv) {
    const int bb = (kv & 1) * 16384;
    __builtin_amdgcn_s_barrier();
    if (kv < 31) {
      const size_t kvb = (size_t)(kv + 1) * 64;
      char* buf = sm + (16384 - bb);
      gld16(Kb + base + kvb * 64 + offK,      (u16*)(buf + db));
      gld16(Kb + base + kvb * 64 + offK + 32, (u16*)(buf + 4096 + db));
      gld16(Vt + base + kvb + offV,           (u16*)(buf + 8192 + db));
      gld16(Vt + base + kvb + offV + 32,      (u16*)(buf + 12288 + db));
      asm volatile("s_waitcnt vmcnt(4)" ::: "memory");  // prev tile landed
    } else {
      asm volatile("s_waitcnt vmcnt(0)" ::: "memory");
    }
    __builtin_amdgcn_s_barrier();

    const char* smb = sm + bb + rdo;

    // ---- S^T = K Q^T (bf16; Q pre-scaled by 0.125*log2e)
    f32x4 s[2][4] = {};
    __builtin_amdgcn_s_setprio(1);
    #pragma unroll
    for (int c = 0; c < 4; ++c)
      #pragma unroll
      for (int ks = 0; ks < 2; ++ks) {
        bf16x8 kb_ = *(const bf16x8*)(smb + ks * 4096 + c * 1024);
        s[0][c] = MFMA(kb_, qh[0][ks], s[0][c]);
        s[1][c] = MFMA(kb_, qh[1][ks], s[1][c]);
      }
    __builtin_amdgcn_s_setprio(0);

    // ---- per-group row max (16 local) + 2-shfl cross reduce over h-lanes
    float pm[2];
    #pragma unroll
    for (int g = 0; g < 2; ++g) {
      float m0 = fmaxf(fmaxf(s[g][0][0], s[g][0][1]), s[g][0][2]);
      float m1 = fmaxf(fmaxf(s[g][0][3], s[g][1][0]), s[g][1][1]);
      float m2 = fmaxf(fmaxf(s[g][1][2], s[g][1][3]), s[g][2][0]);
      float m3 = fmaxf(fmaxf(s[g][2][1], s[g][2][2]), s[g][2][3]);
      float m4 = fmaxf(fmaxf(s[g][3][0], s[g][3][1]), s[g][3][2]);
      float m5 = fmaxf(fmaxf(m0, m1), m2);
      float p  = fmaxf(fmaxf(fmaxf(m3, m4), s[g][3][3]), m5);
      p = fmaxf(p, __shfl_xor(p, 16, 64));
      p = fmaxf(p, __shfl_xor(p, 32, 64));
      pm[g] = p;
    }

    // ---- defer-rescale (THR=7 in log2; P bounded by 128)
    if (__any((pm[0] > mrun[0] + 7.0f) || (pm[1] > mrun[1] + 7.0f))) {
      #pragma unroll
      for (int g = 0; g < 2; ++g) {
        float mnew = fmaxf(mrun[g], pm[g]);
        float scl = fexp2(mrun[g] - mnew);
        mrun[g] = mnew;
        #pragma unroll
        for (int r = 0; r < 4; ++r) {
          float sq = u2f((unsigned)__builtin_amdgcn_ds_bpermute(
              (20 * h + r) * 4, (int)f2u(scl)));
          os[g][r] *= sq;
          #pragma unroll
          for (int dg = 0; dg < 4; ++dg) o[g][dg][r] *= sq;
        }
      }
    }

    // ---- P = exp2(S - mrun) -> bf16 pairs -> per-wave LDS [32q][64kv]
    #pragma unroll
    for (int g = 0; g < 2; ++g)
      #pragma unroll
      for (int c = 0; c < 4; ++c) {
        int w0 = cvtpk(fexp2(s[g][c][0] - mrun[g]),
                       fexp2(s[g][c][1] - mrun[g]));
        int w1 = cvtpk(fexp2(s[g][c][2] - mrun[g]),
                       fexp2(s[g][c][3] - mrun[g]));
        int* dst = (int*)(pb + g * 2048 + prow + ((c * 32 + h * 8) ^ pxor));
        dst[0] = w0; dst[1] = w1;
      }

    // ---- PV + row-sum (P A-frags re-read from LDS; same-wave, no barrier)
    __builtin_amdgcn_s_setprio(1);
    #pragma unroll
    for (int ch = 0; ch < 2; ++ch) {
      bf16x8 pa0 = *(const bf16x8*)(pb + prow +
                                    ((ch * 64 + h * 16) ^ pxor));
      bf16x8 pa1 = *(const bf16x8*)(pb + 2048 + prow +
                                    ((ch * 64 + h * 16) ^ pxor));
      os[0] = MFMA(pa0, ones, os[0]);
      os[1] = MFMA(pa1, ones, os[1]);
      #pragma unroll
      for (int dg = 0; dg < 4; ++dg) {
        bf16x8 vb = *(const bf16x8*)(smb + 8192 + ch * 4096 + dg * 1024);
        o[0][dg] = MFMA(pa0, vb, o[0][dg]);
        o[1][dg] = MFMA(pa1, vb, o[1][dg]);
      }
    }
    __builtin_amdgcn_s_setprio(0);
  }

  // ---- normalize (os[g][r] = rowsum for q = g*16+h*4+r), write AO bf16
  const int b_ = bh >> 3, head = bh & 7;
  #pragma unroll
  for (int g = 0; g < 2; ++g)
    #pragma unroll
    for (int r = 0; r < 4; ++r) {
      const float inv = 1.0f / os[g][r];
      const int row = qr0 + g * 16 + h * 4 + r;
      #pragma unroll
      for (int dg = 0; dg < 4; ++dg) {
        AO[((size_t)(b_ * 2048 + row)) * 512 + head * 64 + dg * 16 + x] =
            f2bf(o[g][dg][r] * inv);
      }
    }
}

// ---------------------------------------------------------------------------
extern "C" void kernel_launch(void* const* d_in, const int* in_sizes, int n_in,
                              void* d_out, int out_size, void* d_ws, size_t ws_size,
                              hipStream_t stream) {
  const float* x    = (const float*)d_in[0];
  const float* wqkv = (const float*)d_in[1];
  const float* wout = (const float*)d_in[2];
  const float* bout = (const float*)d_in[3];
  float* out = (float*)d_out;

  char* w = (char*)d_ws;
  u16* xh  = (u16*)(w + 0);           // 8192x512 bf16
  u16* wqh = (u16*)(w + 16777216);    // WqkvT [1536][512]
  u16* wql = (u16*)(w + 18350080);
  u16* woh = (u16*)(w + 19922944);    // WoutT [512][512]
  u16* wol = (u16*)(w + 20447232);    // (written, unused)
  u16* Qb  = (u16*)(w + 20971520);    // [32][2048][64] bf16 (pre-scaled)
  u16* Kb  = (u16*)(w + 37748736);    // [32][2048][64] bf16
  u16* Vt  = (u16*)(w + 46137344);    // [32][64][2048] bf16
  u16* AO  = (u16*)(w + 54525952);    // [8192][512] bf16; end 62914560

  k_cast  <<<4096, 256, 0, stream>>>(x, xh, 4194304);
  k_tsplit<<<3072, 256, 0, stream>>>(wqkv, wqh, wql, 1536, 786432);
  k_tsplit<<<1024, 256, 0, stream>>>(wout, woh, wol, 512, 262144);
  k_gemm_qkv<<<dim3(64, 12), 256, 0, stream>>>(xh, wqh, wql, Qb, Kb, Vt);
  k_attn<<<512, 256, 0, stream>>>(Qb, Kb, Vt, AO);
  k_gemm_out<<<dim3(64, 4), 256, 0, stream>>>(AO, woh, bout, out);
}